// Round 2
// baseline (461.095 us; speedup 1.0000x reference)
//
#include <hip/hip_runtime.h>

// Problem dims (fixed by the reference): B=256, T=100, D=1024, H=128, C=5
constexpr int Bsz = 256;
constexpr int Tn  = 100;
constexpr int Dn  = 1024;
constexpr int Hn  = 128;
constexpr int Cn  = 5;

// float64 values of np.exp(-1/10), np.exp(-1/20) (long literals -> correctly
// rounded doubles)
#define D1 0.9048374180359595731642491
#define D2 0.9512294245007140090914253

// ---------------------------------------------------------------------------
// Phase 1: Hc[r,128] = X[row(r),1024] @ W1[1024,128]   (fp64 accumulate)
// r indexes a T-chunk: r -> (b = r/Tc, t = t0 + r%Tc), row = b*Tn + t.
// Tile 64(M) x 128(N), BK=16, 256 threads, 4x8 fp64 register tile each.
// NO bias here: reference is left-assoc (v*d + h) + b1.
// ---------------------------------------------------------------------------
constexpr int TILE_M = 64;
constexpr int BKc    = 16;

__global__ __launch_bounds__(256) void gemm_xw1_f64(
    const float* __restrict__ X, const float* __restrict__ W1,
    double* __restrict__ Hc, int t0, int Tc)
{
  __shared__ float As[BKc][TILE_M];   // As[k][m]
  __shared__ float Bs[BKc][Hn];       // Bs[k][n]

  const int tid = threadIdx.x;
  const int ty4 = (tid >> 4) * 4;     // m rows ty4 .. ty4+3
  const int tx8 = (tid & 15) * 8;     // n cols tx8 .. tx8+7
  const int m0  = blockIdx.x * TILE_M;

  // A staging: 64 rows x 16 k = 256 float4, one per thread
  const int rowA = tid >> 2;          // 0..63
  const int qa   = (tid & 3) * 4;     // k offset 0,4,8,12
  // B staging: 16 k x 128 n = 512 float4, two per thread
  const int kB0  = tid >> 5;          // 0..7
  const int nB0  = (tid & 31) * 4;
  const int kB1  = kB0 + 8;

  // chunk-row -> global X row
  const int r    = m0 + rowA;
  const int bidx = r / Tc;
  const int tl   = r - bidx * Tc;
  const int grow = bidx * Tn + t0 + tl;

  const float* Aptr  = X  + (size_t)grow * Dn + qa;
  const float* Bptr0 = W1 + (size_t)kB0 * Hn + nB0;
  const float* Bptr1 = W1 + (size_t)kB1 * Hn + nB0;

  double acc[4][8];
  #pragma unroll
  for (int i = 0; i < 4; ++i)
    #pragma unroll
    for (int j = 0; j < 8; ++j) acc[i][j] = 0.0;

  float4 pa  = *(const float4*)(Aptr);
  float4 pb0 = *(const float4*)(Bptr0);
  float4 pb1 = *(const float4*)(Bptr1);

  constexpr int NC = Dn / BKc;        // 64 K-chunks
  for (int c = 0; c < NC; ++c) {
    __syncthreads();
    As[qa + 0][rowA] = pa.x;
    As[qa + 1][rowA] = pa.y;
    As[qa + 2][rowA] = pa.z;
    As[qa + 3][rowA] = pa.w;
    *(float4*)&Bs[kB0][nB0] = pb0;
    *(float4*)&Bs[kB1][nB0] = pb1;
    __syncthreads();

    if (c + 1 < NC) {
      const int k0 = (c + 1) * BKc;
      pa  = *(const float4*)(Aptr + k0);
      pb0 = *(const float4*)(Bptr0 + (size_t)k0 * Hn);
      pb1 = *(const float4*)(Bptr1 + (size_t)k0 * Hn);
    }

    #pragma unroll
    for (int kk = 0; kk < BKc; ++kk) {
      float4 av  = *(const float4*)&As[kk][ty4];
      float4 b0v = *(const float4*)&Bs[kk][tx8];
      float4 b1v = *(const float4*)&Bs[kk][tx8 + 4];
      double ad[4] = {(double)av.x, (double)av.y, (double)av.z, (double)av.w};
      double bd[8] = {(double)b0v.x, (double)b0v.y, (double)b0v.z, (double)b0v.w,
                      (double)b1v.x, (double)b1v.y, (double)b1v.z, (double)b1v.w};
      #pragma unroll
      for (int i = 0; i < 4; ++i)
        #pragma unroll
        for (int j = 0; j < 8; ++j)
          acc[i][j] = fma(ad[i], bd[j], acc[i][j]);
    }
  }

  #pragma unroll
  for (int i = 0; i < 4; ++i) {
    double* orow = Hc + (size_t)(m0 + ty4 + i) * Hn + tx8;
    #pragma unroll
    for (int j = 0; j < 8; j += 2) {
      double2 o; o.x = acc[i][j]; o.y = acc[i][j + 1];
      *(double2*)(orow + j) = o;
    }
  }
}

// ---------------------------------------------------------------------------
// Phase 2: per-batch-row LIF scan over t in [t0, t0+Tc), fp64 state in ws.
// One 64-lane wave per batch row; each lane owns 2 hidden neurons.
// ---------------------------------------------------------------------------
__global__ __launch_bounds__(64) void snn_scan_f64(
    const double* __restrict__ Hc, const float* __restrict__ b1,
    const float* __restrict__ W2, const float* __restrict__ b2,
    double* __restrict__ v1s, double* __restrict__ v2s,
    double* __restrict__ accs, float* __restrict__ out, int t0, int Tc)
{
#pragma clang fp contract(off)
  const int b    = blockIdx.x;
  const int lane = threadIdx.x;
  const int j0   = lane * 2;

  double w2a[Cn], w2b[Cn], bb2[Cn];
  #pragma unroll
  for (int c = 0; c < Cn; ++c) {
    w2a[c] = (double)W2[(size_t)j0 * Cn + c];
    w2b[c] = (double)W2[(size_t)(j0 + 1) * Cn + c];
    bb2[c] = (double)b2[c];
  }
  const double b1a = (double)b1[j0];
  const double b1b = (double)b1[j0 + 1];

  double v1a, v1b, v2[Cn], acc[Cn];
  if (t0 == 0) {
    v1a = 0.0; v1b = 0.0;
    #pragma unroll
    for (int c = 0; c < Cn; ++c) { v2[c] = 0.0; acc[c] = 0.0; }
  } else {
    v1a = v1s[(size_t)b * Hn + j0];
    v1b = v1s[(size_t)b * Hn + j0 + 1];
    #pragma unroll
    for (int c = 0; c < Cn; ++c) {
      v2[c]  = v2s[(size_t)b * Cn + c];
      acc[c] = accs[(size_t)b * Cn + c];
    }
  }

  const double* hp = Hc + (size_t)b * Tc * Hn + j0;
  double2 hnext = *(const double2*)hp;

  for (int t = 0; t < Tc; ++t) {
    const double2 hc = hnext;
    const int tn = (t + 1 < Tc) ? (t + 1) : t;
    hnext = *(const double2*)(hp + (size_t)tn * Hn);

    // v1 = (v1*d1 + h) + b1  (left-assoc, separate roundings)
    v1a = (v1a * D1 + hc.x) + b1a;
    v1b = (v1b * D1 + hc.y) + b1b;
    const double s1a = (v1a >= 1.0) ? 1.0 : 0.0;
    const double s1b = (v1b >= 1.0) ? 1.0 : 0.0;
    v1a = (v1a >= 1.0) ? 0.0 : v1a;
    v1b = (v1b >= 1.0) ? 0.0 : v1b;

    // p[c] = sum_j s1[j] * W2[j,c]  (fp64 butterfly; order-insensitive at 1e-16)
    double p[Cn];
    #pragma unroll
    for (int c = 0; c < Cn; ++c)
      p[c] = s1a * w2a[c] + s1b * w2b[c];
    #pragma unroll
    for (int off = 32; off > 0; off >>= 1) {
      #pragma unroll
      for (int c = 0; c < Cn; ++c)
        p[c] += __shfl_xor(p[c], off);
    }

    // v2 = ((v2*d2) + p) + b2
    #pragma unroll
    for (int c = 0; c < Cn; ++c) {
      const double v = ((v2[c] * D2) + p[c]) + bb2[c];
      const double s2 = (v >= 1.0) ? 1.0 : 0.0;
      v2[c]  = (v >= 1.0) ? 0.0 : v;
      acc[c] += s2;
    }
  }

  // persist state for next chunk
  v1s[(size_t)b * Hn + j0]     = v1a;
  v1s[(size_t)b * Hn + j0 + 1] = v1b;
  if (lane == 0) {
    #pragma unroll
    for (int c = 0; c < Cn; ++c) {
      v2s[(size_t)b * Cn + c]  = v2[c];
      accs[(size_t)b * Cn + c] = acc[c];
    }
    if (t0 + Tc == Tn) {
      #pragma unroll
      for (int c = 0; c < Cn; ++c)
        out[(size_t)b * Cn + c] = (float)(acc[c] / 100.0);
    }
  }
}

// ---------------------------------------------------------------------------
extern "C" void kernel_launch(void* const* d_in, const int* in_sizes, int n_in,
                              void* d_out, int out_size, void* d_ws, size_t ws_size,
                              hipStream_t stream) {
  const float* X  = (const float*)d_in[0];   // [B,T,D]
  const float* W1 = (const float*)d_in[1];   // [D,H]
  const float* b1 = (const float*)d_in[2];   // [H]
  const float* W2 = (const float*)d_in[3];   // [H,C]
  const float* b2 = (const float*)d_in[4];   // [C]
  float* out = (float*)d_out;                // [B,C]

  // pick largest T-chunk whose h-buffer + state fits in ws
  const size_t stateDoubles = (size_t)Bsz * Hn + 2 * (size_t)Bsz * Cn;
  static const int cands[] = {100, 50, 25, 20, 10, 5, 4, 2, 1};
  int Tc = 1;
  for (int i = 0; i < 9; ++i) {
    const size_t need = ((size_t)Bsz * cands[i] * Hn + stateDoubles) * sizeof(double);
    if (need <= ws_size) { Tc = cands[i]; break; }
  }

  double* Hc   = (double*)d_ws;                      // [B*Tc, H]
  double* v1s  = Hc  + (size_t)Bsz * Tc * Hn;        // [B, H]
  double* v2s  = v1s + (size_t)Bsz * Hn;             // [B, C]
  double* accs = v2s + (size_t)Bsz * Cn;             // [B, C]

  for (int t0 = 0; t0 < Tn; t0 += Tc) {
    gemm_xw1_f64<<<dim3((Bsz * Tc) / TILE_M), dim3(256), 0, stream>>>(X, W1, Hc, t0, Tc);
    snn_scan_f64<<<dim3(Bsz), dim3(64), 0, stream>>>(Hc, b1, W2, b2,
                                                     v1s, v2s, accs, out, t0, Tc);
  }
}